// Round 1
// baseline (276.465 us; speedup 1.0000x reference)
//
#include <hip/hip_runtime.h>
#include <math.h>

#define T_LEN 200
#define D_DIM 64
#define H1_N 80
#define H2_N 40
#define CONST_MIN_F (-4294967295.0f)

__device__ __forceinline__ float sigmoidf_(float x) {
    return 1.0f / (1.0f + __expf(-x));
}

// Wbc[i] = W1[(64+d)*80+h] - W1[(128+d)*80+h]  (i = d*80+h, i < 5120)
__global__ void prep_kernel(const float* __restrict__ W1, float* __restrict__ Wbc) {
    int i = blockIdx.x * 256 + threadIdx.x;
    if (i < 64 * 80) Wbc[i] = W1[64 * 80 + i] - W1[128 * 80 + i];
}

__global__ __launch_bounds__(256) void din_kernel(
    const float* __restrict__ q,    // [B,64]
    const float* __restrict__ k,    // [B,200,64]
    const float* __restrict__ v,    // [B,200,64]
    const int*   __restrict__ mask, // [B,200]
    const float* __restrict__ W1,   // [256,80]
    const float* __restrict__ b1,   // [80]
    const float* __restrict__ W2,   // [80,40]
    const float* __restrict__ b2,   // [40]
    const float* __restrict__ Wf,   // [40]
    const float* __restrict__ bf,   // [1]
    const float* __restrict__ Wbc,  // [64,80] precomputed (W1b - W1c)
    float* __restrict__ out)        // [B,64]
{
    __shared__ float q_lds[2][64];
    __shared__ float A_lds[2][80];
    __shared__ float sm[2][256];       // logits, then softmax weights
    __shared__ short tlist[2][T_LEN];
    __shared__ int   cnts[2][4];
    __shared__ float red[2][128];

    const int tid   = threadIdx.x;
    const int half  = tid >> 7;        // 0/1 : which b this half-block handles
    const int ltid  = tid & 127;       // 0..127 within half
    const int wave  = tid >> 6;        // 0..3
    const int wloc  = wave & 1;        // wave index within half
    const int lane  = tid & 63;
    const long b    = (long)blockIdx.x * 2 + half;

    const float* kb = k + b * (T_LEN * D_DIM);
    const float* vb = v + b * (T_LEN * D_DIM);
    const int*   mb = mask + b * T_LEN;

    // ---- load q row ----
    if (ltid < 64) q_lds[half][ltid] = q[b * 64 + ltid];
    __syncthreads();

    // ---- A[h] = b1[h] + sum_d q[d] * (W1a[d][h] + W1c[d][h]) ----
    if (ltid < H1_N) {
        float acc = b1[ltid];
        for (int d = 0; d < 64; ++d) {
            float qd = q_lds[half][d];
            acc += qd * (W1[d * 80 + ltid] + W1[(128 + d) * 80 + ltid]);
        }
        A_lds[half][ltid] = acc;
    }

    // ---- build deterministic compacted list of unmasked t ----
    // t0 = ltid (0..127), t1 = ltid+128 (valid if < 200)
    int t0 = ltid;
    int t1 = ltid + 128;
    bool f0 = (mb[t0] != 0);
    bool f1 = (t1 < T_LEN) && (mb[t1] != 0);
    unsigned long long bal0 = __ballot(f0);
    unsigned long long bal1 = __ballot(f1);
    if (lane == 0) {
        cnts[half][wloc]     = (int)__popcll(bal0);
        cnts[half][2 + wloc] = (int)__popcll(bal1);
    }
    // init logits (placeholders for unmasked, CONST_MIN for masked, -inf pad)
    sm[half][t0] = f0 ? 0.f : CONST_MIN_F;                       // t0 < 200 always
    sm[half][t1] = (t1 < T_LEN) ? (f1 ? 0.f : CONST_MIN_F) : -INFINITY;
    __syncthreads();

    int c0 = cnts[half][0], c1 = cnts[half][1];
    int c2 = cnts[half][2], c3 = cnts[half][3];
    int tot = c0 + c1 + c2 + c3;
    unsigned long long ltm = (1ull << lane) - 1ull;
    int base0 = (wloc == 0) ? 0 : c0;
    int base1 = (wloc == 0) ? (c0 + c1) : (c0 + c1 + c2);
    if (f0) tlist[half][base0 + (int)__popcll(bal0 & ltm)] = (short)t0;
    if (f1) tlist[half][base1 + (int)__popcll(bal1 & ltm)] = (short)t1;
    __syncthreads();

    // ---- MLP on compacted list ----
    const float* W1d = W1 + 192 * 80;   // (q*k) block
    for (int i = ltid; i < tot; i += 128) {
        int t = tlist[half][i];
        const float4* krow4 = (const float4*)(kb + t * 64);

        float z[H1_N];
        #pragma unroll
        for (int h = 0; h < H1_N; ++h) z[h] = A_lds[half][h];

        float4 kv = krow4[0];
        for (int d4 = 0; d4 < 16; ++d4) {
            float4 kcur = kv;
            kv = krow4[(d4 + 1) & 15];          // manual prefetch
            float kds[4] = {kcur.x, kcur.y, kcur.z, kcur.w};
            #pragma unroll
            for (int j = 0; j < 4; ++j) {
                int d = 4 * d4 + j;
                float kd = kds[j];
                float kq = kd * q_lds[half][d];
                const float* wb = Wbc + d * 80;
                const float* wd = W1d + d * 80;
                #pragma unroll
                for (int h4 = 0; h4 < 20; ++h4) {
                    float4 wbv = *(const float4*)(wb + 4 * h4);
                    float4 wdv = *(const float4*)(wd + 4 * h4);
                    z[4 * h4 + 0] += kd * wbv.x + kq * wdv.x;
                    z[4 * h4 + 1] += kd * wbv.y + kq * wdv.y;
                    z[4 * h4 + 2] += kd * wbv.z + kq * wdv.z;
                    z[4 * h4 + 3] += kd * wbv.w + kq * wdv.w;
                }
            }
        }
        #pragma unroll
        for (int h = 0; h < H1_N; ++h) z[h] = sigmoidf_(z[h]);

        float logit = bf[0];
        #pragma unroll 1
        for (int g4 = 0; g4 < 10; ++g4) {
            float4 acc = *(const float4*)(b2 + 4 * g4);
            #pragma unroll
            for (int h = 0; h < H1_N; ++h) {
                float4 w2v = *(const float4*)(W2 + h * 40 + 4 * g4);
                acc.x += z[h] * w2v.x;
                acc.y += z[h] * w2v.y;
                acc.z += z[h] * w2v.z;
                acc.w += z[h] * w2v.w;
            }
            float4 wfv = *(const float4*)(Wf + 4 * g4);
            logit += wfv.x * sigmoidf_(acc.x) + wfv.y * sigmoidf_(acc.y)
                   + wfv.z * sigmoidf_(acc.z) + wfv.w * sigmoidf_(acc.w);
        }
        sm[half][t] = logit;
    }
    __syncthreads();

    // ---- softmax over sm[half][0..255] (per half) ----
    float l0 = sm[half][ltid];
    float l1 = sm[half][ltid + 128];
    float m = fmaxf(l0, l1);
    #pragma unroll
    for (int off = 32; off > 0; off >>= 1) m = fmaxf(m, __shfl_xor(m, off));
    if (lane == 0) red[half][wloc] = m;
    __syncthreads();
    float bmax = fmaxf(red[half][0], red[half][1]);
    float e0 = __expf(l0 - bmax);
    float e1 = __expf(l1 - bmax);   // -inf pad -> 0
    float s = e0 + e1;
    #pragma unroll
    for (int off = 32; off > 0; off >>= 1) s += __shfl_xor(s, off);
    if (lane == 0) red[half][2 + wloc] = s;
    __syncthreads();
    float bsum = red[half][2] + red[half][3];
    float inv = 1.0f / bsum;
    sm[half][ltid]       = e0 * inv;
    sm[half][ltid + 128] = e1 * inv;
    __syncthreads();

    // ---- weighted sum of v (only unmasked rows contribute, unless all masked) ----
    int d  = ltid & 63;
    int c  = ltid >> 6;               // 0/1
    int n_pv = (tot > 0) ? tot : T_LEN;   // all-masked degenerate: uniform weights
    float acc = 0.f;
    for (int i = c; i < n_pv; i += 2) {
        int t = (tot > 0) ? (int)tlist[half][i] : i;
        acc += sm[half][t] * vb[t * 64 + d];
    }
    red[half][c * 64 + d] = acc;
    __syncthreads();
    if (ltid < 64) out[b * 64 + ltid] = red[half][ltid] + red[half][64 + ltid];
}

extern "C" void kernel_launch(void* const* d_in, const int* in_sizes, int n_in,
                              void* d_out, int out_size, void* d_ws, size_t ws_size,
                              hipStream_t stream) {
    const float* q    = (const float*)d_in[0];
    const float* k    = (const float*)d_in[1];
    const float* v    = (const float*)d_in[2];
    const int*   mask = (const int*)d_in[3];
    const float* W1   = (const float*)d_in[4];
    const float* b1   = (const float*)d_in[5];
    const float* W2   = (const float*)d_in[6];
    const float* b2   = (const float*)d_in[7];
    const float* Wf   = (const float*)d_in[8];
    const float* bf   = (const float*)d_in[9];
    float* out = (float*)d_out;
    float* Wbc = (float*)d_ws;   // 64*80 floats = 20.5 KB scratch

    hipLaunchKernelGGL(prep_kernel, dim3(20), dim3(256), 0, stream, W1, Wbc);
    // B = 2048, two b's per block
    hipLaunchKernelGGL(din_kernel, dim3(1024), dim3(256), 0, stream,
                       q, k, v, mask, W1, b1, W2, b2, Wf, bf, Wbc, out);
}

// Round 2
// 249.830 us; speedup vs baseline: 1.1066x; 1.1066x over previous
//
#include <hip/hip_runtime.h>
#include <math.h>

#define T_LEN 200
#define CONST_MIN_F (-4294967295.0f)

typedef float f4u __attribute__((ext_vector_type(4), aligned(4)));
typedef float f2u __attribute__((ext_vector_type(2), aligned(4)));

__device__ __forceinline__ float sigmoidf_(float x) {
    return 1.0f / (1.0f + __expf(-x));
}
__device__ __forceinline__ unsigned int pk_bf16(float lo, float hi) {
    unsigned int r;
    asm("v_cvt_pk_bf16_f32 %0, %1, %2" : "=v"(r) : "v"(lo), "v"(hi));
    return r;
}
__device__ __forceinline__ float bf_lo(unsigned int u) {
    union { unsigned int ui; float f; } c; c.ui = u << 16; return c.f;
}
__device__ __forceinline__ float bf_hi(unsigned int u) {
    union { unsigned int ui; float f; } c; c.ui = u & 0xffff0000u; return c.f;
}

// ws[0..5120)      : Wbc = W1b - W1c         (rows 0..63 of Wcat)
// ws[5120..10240)  : W1d                      (rows 64..127 of Wcat)
// ws[10240..15360) : Wsum = W1a + W1c         (for the per-b q-term A)
__global__ void prep_kernel(const float* __restrict__ W1, float* __restrict__ ws) {
    int i = blockIdx.x * 256 + threadIdx.x;
    if (i < 5120) {
        ws[i]         = W1[5120 + i] - W1[10240 + i];
        ws[5120 + i]  = W1[15360 + i];
        ws[10240 + i] = W1[i] + W1[10240 + i];
    }
}

__global__ __launch_bounds__(256) void din_kernel(
    const float* __restrict__ q,    // [B,64]
    const float* __restrict__ k,    // [B,200,64]
    const float* __restrict__ v,    // [B,200,64]
    const int*   __restrict__ mask, // [B,200]
    const float* __restrict__ b1,   // [80]
    const float* __restrict__ W2,   // [80,40]
    const float* __restrict__ b2,   // [40]
    const float* __restrict__ Wf,   // [40]
    const float* __restrict__ bf,   // [1]
    const float* __restrict__ ws,   // Wcat[128][80] | Wsum[64][80]
    float* __restrict__ out)        // [B,64]
{
    __shared__ unsigned short x_s[128 * 128]; // 32 KB: [d 0..127][item 0..127] bf16
    __shared__ unsigned short h_s[80 * 128];  // 20 KB: [h][item] bf16 (reused as f32 red)
    __shared__ float sm_s[256];
    __shared__ float q_s[64];
    __shared__ float A_s[80];
    __shared__ float red8[8];
    __shared__ short tlist[T_LEN];
    __shared__ int   cnts[4];

    const int tid  = threadIdx.x;
    const int lane = tid & 63;
    const int wid  = tid >> 6;
    const int ig   = tid >> 3;   // 0..31: item group (4 items each)
    const int hs   = tid & 7;    // 0..7 : h-slice (10 h) / g-slice (5 g)
    const long b   = blockIdx.x;

    const float* kb = k + b * (T_LEN * 64);
    const float* vb = v + b * (T_LEN * 64);
    const int*   mb = mask + b * T_LEN;
    const float* Wcat = ws;
    const float* Wsum = ws + 10240;

    if (tid < 64) q_s[tid] = q[b * 64 + tid];
    bool f = (tid < T_LEN) && (mb[tid] != 0);
    unsigned long long bal = __ballot(f);
    if (lane == 0) cnts[wid] = (int)__popcll(bal);
    sm_s[tid] = (tid < T_LEN) ? (f ? 0.f : CONST_MIN_F) : -INFINITY;
    __syncthreads();

    const int tot = cnts[0] + cnts[1] + cnts[2] + cnts[3];
    {
        int basew = 0;
        #pragma unroll
        for (int w = 0; w < 4; ++w) if (w < wid) basew += cnts[w];
        if (f) {
            unsigned long long ltm = (1ull << lane) - 1ull;
            tlist[basew + (int)__popcll(bal & ltm)] = (short)tid;
        }
    }
    if (tid < 80) {
        float acc = b1[tid];
        for (int d = 0; d < 64; ++d) acc = fmaf(q_s[d], Wsum[d * 80 + tid], acc);
        A_s[tid] = acc;
    }
    __syncthreads();

    const float bf0 = bf[0];
    float wfv[5];
    #pragma unroll
    for (int j = 0; j < 5; ++j) wfv[j] = Wf[hs * 5 + j];

    unsigned int* x32 = (unsigned int*)x_s;
    unsigned int* h32 = (unsigned int*)h_s;

    const int npass = (tot + 127) >> 7;
    for (int p = 0; p < npass; ++p) {
        const int base = p << 7;
        const int cnt  = min(tot - base, 128);

        // ---- stage x = [k | k*q] bf16, transposed [d][item] ----
        #pragma unroll
        for (int s = 0; s < 4; ++s) {
            int u  = tid + (s << 8);
            int ip = u & 63;      // item pair -> items 2ip, 2ip+1
            int d4 = u >> 6;      // 0..15
            int t0 = tlist[base + min(2 * ip,     cnt - 1)];
            int t1 = tlist[base + min(2 * ip + 1, cnt - 1)];
            float4 a4 = *(const float4*)(kb + t0 * 64 + d4 * 4);
            float4 c4 = *(const float4*)(kb + t1 * 64 + d4 * 4);
            float aa[4] = {a4.x, a4.y, a4.z, a4.w};
            float cc[4] = {c4.x, c4.y, c4.z, c4.w};
            #pragma unroll
            for (int j = 0; j < 4; ++j) {
                int d = 4 * d4 + j;
                float qd = q_s[d];
                x32[d * 64 + ip]        = pk_bf16(aa[j], cc[j]);
                x32[(64 + d) * 64 + ip] = pk_bf16(aa[j] * qd, cc[j] * qd);
            }
        }
        __syncthreads();

        // ---- layer 1: z[4 items][10 h] ----
        float zz[40];
        #pragma unroll
        for (int i = 0; i < 4; ++i)
            #pragma unroll
            for (int j = 0; j < 10; ++j) zz[i * 10 + j] = A_s[hs * 10 + j];

        const float* wrow = Wcat + hs * 10;
        #pragma unroll 2
        for (int d = 0; d < 128; ++d) {
            uint2 xv = *(const uint2*)(x_s + d * 128 + ig * 4);
            float xx[4] = {bf_lo(xv.x), bf_hi(xv.x), bf_lo(xv.y), bf_hi(xv.y)};
            f4u w0 = *(const f4u*)(wrow);
            f4u w1 = *(const f4u*)(wrow + 4);
            f2u w2v = *(const f2u*)(wrow + 8);
            float wv[10] = {w0.x, w0.y, w0.z, w0.w, w1.x, w1.y, w1.z, w1.w, w2v.x, w2v.y};
            #pragma unroll
            for (int i = 0; i < 4; ++i)
                #pragma unroll
                for (int j = 0; j < 10; ++j)
                    zz[i * 10 + j] = fmaf(xx[i], wv[j], zz[i * 10 + j]);
            wrow += 80;
        }

        // ---- sigmoid + write h transposed [h][item] bf16 ----
        #pragma unroll
        for (int j = 0; j < 10; ++j) {
            float h0 = sigmoidf_(zz[0 * 10 + j]);
            float h1 = sigmoidf_(zz[1 * 10 + j]);
            float h2 = sigmoidf_(zz[2 * 10 + j]);
            float h3 = sigmoidf_(zz[3 * 10 + j]);
            h32[(hs * 10 + j) * 64 + ig * 2]     = pk_bf16(h0, h1);
            h32[(hs * 10 + j) * 64 + ig * 2 + 1] = pk_bf16(h2, h3);
        }
        __syncthreads();

        // ---- layer 2: z2[4 items][5 g] ----
        float z2[20];
        #pragma unroll
        for (int i = 0; i < 4; ++i)
            #pragma unroll
            for (int j = 0; j < 5; ++j) z2[i * 5 + j] = b2[hs * 5 + j];

        const float* w2r = W2 + hs * 5;
        #pragma unroll 2
        for (int h = 0; h < 80; ++h) {
            uint2 hv = *(const uint2*)(h_s + h * 128 + ig * 4);
            float xx[4] = {bf_lo(hv.x), bf_hi(hv.x), bf_lo(hv.y), bf_hi(hv.y)};
            f4u w0 = *(const f4u*)(w2r);
            float wv[5] = {w0.x, w0.y, w0.z, w0.w, w2r[4]};
            #pragma unroll
            for (int i = 0; i < 4; ++i)
                #pragma unroll
                for (int j = 0; j < 5; ++j)
                    z2[i * 5 + j] = fmaf(xx[i], wv[j], z2[i * 5 + j]);
            w2r += 40;
        }

        float pl[4];
        #pragma unroll
        for (int i = 0; i < 4; ++i) {
            float acc = 0.f;
            #pragma unroll
            for (int j = 0; j < 5; ++j) acc = fmaf(wfv[j], sigmoidf_(z2[i * 5 + j]), acc);
            pl[i] = acc;
        }
        #pragma unroll
        for (int off = 1; off < 8; off <<= 1) {
            #pragma unroll
            for (int i = 0; i < 4; ++i) pl[i] += __shfl_xor(pl[i], off);
        }
        if (hs == 0) {
            #pragma unroll
            for (int i = 0; i < 4; ++i) {
                int idx = ig * 4 + i;
                if (idx < cnt) sm_s[tlist[base + idx]] = pl[i] + bf0;
            }
        }
        __syncthreads();
    }

    // ---- softmax over 256 slots ----
    float l = sm_s[tid];
    float m = l;
    #pragma unroll
    for (int off = 32; off > 0; off >>= 1) m = fmaxf(m, __shfl_xor(m, off));
    if (lane == 0) red8[wid] = m;
    __syncthreads();
    float M = fmaxf(fmaxf(red8[0], red8[1]), fmaxf(red8[2], red8[3]));
    float e = __expf(l - M);
    float ssum = e;
    #pragma unroll
    for (int off = 32; off > 0; off >>= 1) ssum += __shfl_xor(ssum, off);
    if (lane == 0) red8[4 + wid] = ssum;
    __syncthreads();
    float S = red8[4] + red8[5] + red8[6] + red8[7];
    sm_s[tid] = e / S;
    __syncthreads();

    // ---- PV: out[b][d] = sum_t w[t] * v[b][t][d] ----
    float* red = (float*)h_s;
    int dd = tid & 63, c = tid >> 6;
    float acc = 0.f;
    if (tot > 0) {
        for (int i = c; i < tot; i += 4) {
            int t = tlist[i];
            acc = fmaf(sm_s[t], vb[t * 64 + dd], acc);
        }
    } else {
        for (int t = c; t < T_LEN; t += 4)
            acc = fmaf(sm_s[t], vb[t * 64 + dd], acc);
    }
    red[c * 64 + dd] = acc;
    __syncthreads();
    if (tid < 64)
        out[b * 64 + tid] = red[tid] + red[64 + tid] + red[128 + tid] + red[192 + tid];
}

extern "C" void kernel_launch(void* const* d_in, const int* in_sizes, int n_in,
                              void* d_out, int out_size, void* d_ws, size_t ws_size,
                              hipStream_t stream) {
    const float* q    = (const float*)d_in[0];
    const float* k    = (const float*)d_in[1];
    const float* v    = (const float*)d_in[2];
    const int*   mask = (const int*)d_in[3];
    const float* W1   = (const float*)d_in[4];
    const float* b1   = (const float*)d_in[5];
    const float* W2   = (const float*)d_in[6];
    const float* b2   = (const float*)d_in[7];
    const float* Wf   = (const float*)d_in[8];
    const float* bf   = (const float*)d_in[9];
    float* out = (float*)d_out;
    float* ws  = (float*)d_ws;   // 15360 floats = 61.5 KB

    hipLaunchKernelGGL(prep_kernel, dim3(20), dim3(256), 0, stream, W1, ws);
    hipLaunchKernelGGL(din_kernel, dim3(2048), dim3(256), 0, stream,
                       q, k, v, mask, b1, W2, b2, Wf, bf, ws, out);
}

// Round 3
// 168.133 us; speedup vs baseline: 1.6443x; 1.4859x over previous
//
#include <hip/hip_runtime.h>
#include <math.h>

#define T_LEN 200
#define CONST_MIN_F (-4294967295.0f)

typedef short bf8 __attribute__((ext_vector_type(8)));
typedef float f32x4 __attribute__((ext_vector_type(4)));

__device__ __forceinline__ float sigmoidf_(float x){ return 1.0f/(1.0f+__expf(-x)); }
__device__ __forceinline__ unsigned int pk_bf16(float lo, float hi){
  unsigned int r; asm("v_cvt_pk_bf16_f32 %0, %1, %2":"=v"(r):"v"(lo),"v"(hi)); return r;
}

// ws layout:
//   f32    ws[0..5120)      : Wsum[d][h] = W1a + W1c   (for per-b q-term A)
//   ushort fb[0..10240)     : A1 frags (Wcat^T) 20 frags x 64 lanes x 8 elems, bf16
//   ushort fb[10240..14848) : A2 frags (W2^T, padded to 48x96) 9 frags x 512, bf16
// A-fragment layout (16x16x32): row = lane&15, k = (lane>>4)*8 + e
__global__ void prep_kernel(const float* __restrict__ W1, const float* __restrict__ W2,
                            float* __restrict__ ws){
  int i = blockIdx.x*256 + threadIdx.x;
  unsigned short* fb = (unsigned short*)(ws + 5120);
  if (i < 5120) ws[i] = W1[i] + W1[10240 + i];
  if (i < 10240){
    int fi = i >> 9, lane = (i>>3)&63, e = i&7;
    int ht = fi >> 2, ks = fi & 3;
    int h = ht*16 + (lane&15);
    int f = ks*32 + ((lane>>4)<<3) + e;
    float v = (f<64) ? (W1[(64+f)*80+h] - W1[(128+f)*80+h]) : W1[(128+f)*80+h];
    fb[i] = (unsigned short)(pk_bf16(v,v) & 0xffffu);
  }
  if (i < 4608){
    int fi = i >> 9, lane = (i>>3)&63, e = i&7;
    int gt = fi/3, ks = fi - 3*gt;
    int g = gt*16 + (lane&15);
    int h = ks*32 + ((lane>>4)<<3) + e;
    float v = (g<40 && h<80) ? W2[h*40+g] : 0.f;
    fb[10240 + i] = (unsigned short)(pk_bf16(v,v) & 0xffffu);
  }
}

__global__ __launch_bounds__(256) void din_kernel(
    const float* __restrict__ q, const float* __restrict__ k, const float* __restrict__ v,
    const int* __restrict__ mask, const float* __restrict__ b1,
    const float* __restrict__ b2, const float* __restrict__ Wf, const float* __restrict__ bf,
    const float* __restrict__ ws, float* __restrict__ out)
{
  // X / H share this buffer: [128 items][16 kblk][8 bf16], kblk ^= (item&7) swizzle
  __shared__ __align__(16) unsigned int x32[128*64];   // 32 KB
  __shared__ float sm_s[256];
  __shared__ float q_s[64];
  __shared__ float A_s[80];
  __shared__ float b2p[48];
  __shared__ float wfp[48];
  __shared__ float red8[8];
  __shared__ short tlist[T_LEN];
  __shared__ int   cnts[4];

  const int tid  = threadIdx.x;
  const int lane = tid & 63;
  const int wid  = tid >> 6;
  const int lg   = lane >> 4;    // lane group 0..3
  const int lc   = lane & 15;    // col (item) within group
  const long b   = blockIdx.x;

  const float* kb = k + b*(T_LEN*64);
  const float* vb = v + b*(T_LEN*64);
  const int*   mb = mask + b*T_LEN;
  const unsigned short* fbg = (const unsigned short*)(ws + 5120);
  const bf8* A1f = (const bf8*)fbg;            // 20 frags
  const bf8* A2f = (const bf8*)(fbg + 10240);  // 9 frags

  if (tid < 64) q_s[tid] = q[b*64 + tid];
  if (tid < 48){ b2p[tid] = (tid<40)? b2[tid] : 0.f; wfp[tid] = (tid<40)? Wf[tid] : 0.f; }
  bool f = (tid < T_LEN) && (mb[tid] != 0);
  unsigned long long bal = __ballot(f);
  if (lane == 0) cnts[wid] = (int)__popcll(bal);
  sm_s[tid] = (tid < T_LEN) ? (f ? 0.f : CONST_MIN_F) : -INFINITY;
  __syncthreads();

  const int tot = cnts[0]+cnts[1]+cnts[2]+cnts[3];
  {
    int basew = 0;
    #pragma unroll
    for (int w=0; w<4; ++w) if (w<wid) basew += cnts[w];
    if (f){
      unsigned long long ltm = (1ull<<lane)-1ull;
      tlist[basew + (int)__popcll(bal & ltm)] = (short)tid;
    }
  }
  if (tid < 80){
    float acc = b1[tid];
    #pragma unroll 8
    for (int d=0; d<64; ++d) acc = fmaf(q_s[d], ws[d*80+tid], acc);
    A_s[tid] = acc;
  }
  __syncthreads();

  const float bf0 = bf[0];
  const int npass = (tot + 127) >> 7;
  for (int p=0; p<npass; ++p){
    const int base = p << 7;
    const int cnt  = min(tot - base, 128);
    const int nmt  = (cnt + 15) >> 4;

    // ---- stage X = [k | k*q] bf16, swizzled ----
    #pragma unroll
    for (int s=0; s<4; ++s){
      int u   = tid + (s<<8);
      int il  = u >> 3;      // item local 0..127
      int kb8 = u & 7;       // kblk 0..7
      int t = tlist[base + min(il, cnt-1)];
      const float4* kr = (const float4*)(kb + t*64 + kb8*8);
      float4 a = kr[0], c = kr[1];
      float q0=q_s[kb8*8+0],q1=q_s[kb8*8+1],q2=q_s[kb8*8+2],q3=q_s[kb8*8+3];
      float q4=q_s[kb8*8+4],q5=q_s[kb8*8+5],q6=q_s[kb8*8+6],q7=q_s[kb8*8+7];
      uint4 w;
      w.x = pk_bf16(a.x,a.y); w.y = pk_bf16(a.z,a.w);
      w.z = pk_bf16(c.x,c.y); w.w = pk_bf16(c.z,c.w);
      ((uint4*)x32)[il*16 + (kb8 ^ (il&7))] = w;
      uint4 w2;
      w2.x = pk_bf16(a.x*q0, a.y*q1); w2.y = pk_bf16(a.z*q2, a.w*q3);
      w2.z = pk_bf16(c.x*q4, c.y*q5); w2.w = pk_bf16(c.z*q6, c.w*q7);
      ((uint4*)x32)[il*16 + ((kb8+8) ^ (il&7))] = w2;
    }
    __syncthreads();

    // ---- layer 1: D1[h][item] = Wcat^T @ X^T ----
    const int it0 = wid, it1 = wid + 4;
    const bool a0 = it0 < nmt, a1 = it1 < nmt;
    const int item0 = it0*16 + lc, item1 = it1*16 + lc;
    bf8 B0[4], B1v[4];
    #pragma unroll
    for (int ks=0; ks<4; ++ks){
      if (a0) B0[ks]  = *(const bf8*)(x32 + item0*64 + ((ks*4+lg) ^ (item0&7))*4);
      if (a1) B1v[ks] = *(const bf8*)(x32 + item1*64 + ((ks*4+lg) ^ (item1&7))*4);
    }
    f32x4 acc0[5], acc1[5];
    #pragma unroll
    for (int ht=0; ht<5; ++ht){
      #pragma unroll
      for (int r=0; r<4; ++r){
        float av = A_s[ht*16 + lg*4 + r];
        acc0[ht][r] = av; acc1[ht][r] = av;
      }
    }
    #pragma unroll
    for (int ht=0; ht<5; ++ht){
      #pragma unroll
      for (int ks=0; ks<4; ++ks){
        bf8 afr = A1f[(ht*4+ks)*64 + lane];
        if (a0) acc0[ht] = __builtin_amdgcn_mfma_f32_16x16x32_bf16(afr, B0[ks],  acc0[ht], 0,0,0);
        if (a1) acc1[ht] = __builtin_amdgcn_mfma_f32_16x16x32_bf16(afr, B1v[ks], acc1[ht], 0,0,0);
      }
    }
    __syncthreads();   // all X reads done; buffer becomes H

    // zero pad rows h=80..95 (hblk 10,11)
    {
      int il = tid >> 1, hb = 10 + (tid & 1);
      uint4 z; z.x=z.y=z.z=z.w=0u;
      ((uint4*)x32)[il*16 + (hb ^ (il&7))] = z;
    }
    // sigmoid -> H bf16 (same swizzled layout, h is the k-dim now)
    #pragma unroll
    for (int ht=0; ht<5; ++ht){
      #pragma unroll
      for (int rp=0; rp<2; ++rp){
        int h = ht*16 + lg*4 + rp*2;
        if (a0){
          unsigned int wd = pk_bf16(sigmoidf_(acc0[ht][2*rp]), sigmoidf_(acc0[ht][2*rp+1]));
          x32[item0*64 + ((h>>3) ^ (item0&7))*4 + ((h&7)>>1)] = wd;
        }
        if (a1){
          unsigned int wd = pk_bf16(sigmoidf_(acc1[ht][2*rp]), sigmoidf_(acc1[ht][2*rp+1]));
          x32[item1*64 + ((h>>3) ^ (item1&7))*4 + ((h&7)>>1)] = wd;
        }
      }
    }
    __syncthreads();

    // ---- layer 2: D2[g][item] = W2^T @ H^T ----
    bf8 C0[3], C1[3];
    #pragma unroll
    for (int ks=0; ks<3; ++ks){
      if (a0) C0[ks] = *(const bf8*)(x32 + item0*64 + ((ks*4+lg) ^ (item0&7))*4);
      if (a1) C1[ks] = *(const bf8*)(x32 + item1*64 + ((ks*4+lg) ^ (item1&7))*4);
    }
    f32x4 g0[3], g1[3];
    #pragma unroll
    for (int gt=0; gt<3; ++gt){
      #pragma unroll
      for (int r=0; r<4; ++r){
        float bv = b2p[gt*16 + lg*4 + r];
        g0[gt][r] = bv; g1[gt][r] = bv;
      }
    }
    #pragma unroll
    for (int gt=0; gt<3; ++gt){
      #pragma unroll
      for (int ks=0; ks<3; ++ks){
        bf8 afr = A2f[(gt*3+ks)*64 + lane];
        if (a0) g0[gt] = __builtin_amdgcn_mfma_f32_16x16x32_bf16(afr, C0[ks], g0[gt], 0,0,0);
        if (a1) g1[gt] = __builtin_amdgcn_mfma_f32_16x16x32_bf16(afr, C1[ks], g1[gt], 0,0,0);
      }
    }
    // ---- logits = bf + sum_g Wf[g]*sigmoid(z2[g][item]) ----
    float p0 = 0.f, p1 = 0.f;
    #pragma unroll
    for (int gt=0; gt<3; ++gt){
      #pragma unroll
      for (int r=0; r<4; ++r){
        float wf = wfp[gt*16 + lg*4 + r];
        if (a0) p0 = fmaf(wf, sigmoidf_(g0[gt][r]), p0);
        if (a1) p1 = fmaf(wf, sigmoidf_(g1[gt][r]), p1);
      }
    }
    p0 += __shfl_xor(p0, 16); p0 += __shfl_xor(p0, 32);
    p1 += __shfl_xor(p1, 16); p1 += __shfl_xor(p1, 32);
    if (lg == 0){
      if (a0 && it0*16 + lc < cnt) sm_s[tlist[base + it0*16 + lc]] = p0 + bf0;
      if (a1 && it1*16 + lc < cnt) sm_s[tlist[base + it1*16 + lc]] = p1 + bf0;
    }
    __syncthreads();
  }

  // ---- softmax over 256 slots ----
  float l = sm_s[tid];
  float m = l;
  #pragma unroll
  for (int off = 32; off > 0; off >>= 1) m = fmaxf(m, __shfl_xor(m, off));
  if (lane == 0) red8[wid] = m;
  __syncthreads();
  float M = fmaxf(fmaxf(red8[0], red8[1]), fmaxf(red8[2], red8[3]));
  float e = __expf(l - M);
  float ssum = e;
  #pragma unroll
  for (int off = 32; off > 0; off >>= 1) ssum += __shfl_xor(ssum, off);
  if (lane == 0) red8[4 + wid] = ssum;
  __syncthreads();
  float S = red8[4] + red8[5] + red8[6] + red8[7];
  sm_s[tid] = e / S;
  __syncthreads();

  // ---- PV ----
  float* red = (float*)x32;
  int dd = tid & 63, c = tid >> 6;
  float acc = 0.f;
  if (tot > 0){
    for (int i = c; i < tot; i += 4){
      int t = tlist[i];
      acc = fmaf(sm_s[t], vb[t*64 + dd], acc);
    }
  } else {
    for (int t = c; t < T_LEN; t += 4)
      acc = fmaf(sm_s[t], vb[t*64 + dd], acc);
  }
  red[c*64 + dd] = acc;
  __syncthreads();
  if (tid < 64)
    out[b*64 + tid] = red[tid] + red[64 + tid] + red[128 + tid] + red[192 + tid];
}

extern "C" void kernel_launch(void* const* d_in, const int* in_sizes, int n_in,
                              void* d_out, int out_size, void* d_ws, size_t ws_size,
                              hipStream_t stream) {
  const float* q    = (const float*)d_in[0];
  const float* k    = (const float*)d_in[1];
  const float* v    = (const float*)d_in[2];
  const int*   mask = (const int*)d_in[3];
  const float* W1   = (const float*)d_in[4];
  const float* b1   = (const float*)d_in[5];
  const float* W2   = (const float*)d_in[6];
  const float* b2   = (const float*)d_in[7];
  const float* Wf   = (const float*)d_in[8];
  const float* bf   = (const float*)d_in[9];
  float* out = (float*)d_out;
  float* ws  = (float*)d_ws;   // 20480B f32 + 29696B bf16 frags ≈ 50 KB

  hipLaunchKernelGGL(prep_kernel, dim3(40), dim3(256), 0, stream, W1, W2, ws);
  hipLaunchKernelGGL(din_kernel, dim3(2048), dim3(256), 0, stream,
                     q, k, v, mask, b1, b2, Wf, bf, ws, out);
}

// Round 4
// 57.819 us; speedup vs baseline: 4.7816x; 2.9079x over previous
//
#include <hip/hip_runtime.h>
#include <math.h>

#define T_LEN 200
#define CONST_MIN_F (-4294967295.0f)

typedef short bf8 __attribute__((ext_vector_type(8)));
typedef float f32x4 __attribute__((ext_vector_type(4)));

__device__ __forceinline__ float sigmoidf_(float x){ return 1.0f/(1.0f+__expf(-x)); }
__device__ __forceinline__ unsigned int pk_bf16(float lo, float hi){
  unsigned int r; asm("v_cvt_pk_bf16_f32 %0, %1, %2":"=v"(r):"v"(lo),"v"(hi)); return r;
}
union U4B8 { uint4 u; bf8 b; };
__device__ __forceinline__ bf8 pack8(float4 x, float4 y){
  U4B8 r;
  r.u.x = pk_bf16(x.x,x.y); r.u.y = pk_bf16(x.z,x.w);
  r.u.z = pk_bf16(y.x,y.y); r.u.w = pk_bf16(y.z,y.w);
  return r.b;
}
__device__ __forceinline__ bf8 pack8m(float4 x, float4 qx, float4 y, float4 qy){
  U4B8 r;
  r.u.x = pk_bf16(x.x*qx.x, x.y*qx.y); r.u.y = pk_bf16(x.z*qx.z, x.w*qx.w);
  r.u.z = pk_bf16(y.x*qy.x, y.y*qy.y); r.u.w = pk_bf16(y.z*qy.z, y.w*qy.w);
  return r.b;
}

// fb[0..15360)      : A1 frags, 30 frags (ht 0..4 x ks 0..5), K=192 layout:
//                     k-dims 0..63 = k      -> W1b - W1c
//                     k-dims 64..127 = k*q  -> W1d
//                     k-dims 128..191 = q   -> W1a + W1c   (folds the q-term)
// fb[15360..19968)  : A2 frags (W2^T padded to 48x96), 9 frags
// A-frag layout (16x16x32): row = lane&15, k = ks*32 + (lane>>4)*8 + e
__global__ void prep_kernel(const float* __restrict__ W1, const float* __restrict__ W2,
                            unsigned short* __restrict__ fb){
  int i = blockIdx.x*256 + threadIdx.x;
  if (i < 15360){
    int fi = i >> 9;                  // 0..29
    int lane = (i>>3)&63, e = i&7;
    int ht = fi/6, ks = fi%6;
    int h = ht*16 + (lane&15);
    int f = ks*32 + ((lane>>4)<<3) + e;
    float val;
    if (f < 64)        val = W1[(64+f)*80+h] - W1[(128+f)*80+h];
    else if (f < 128)  val = W1[(128+f)*80+h];        // = W1d row (f-64)
    else               val = W1[(f-128)*80+h] + W1[f*80+h];  // W1a + W1c
    fb[i] = (unsigned short)(pk_bf16(val,val) & 0xffffu);
  }
  if (i < 4608){
    int fi = i >> 9;                  // 0..8
    int lane = (i>>3)&63, e = i&7;
    int gt = fi/3, ks = fi%3;
    int g = gt*16 + (lane&15);
    int h = ks*32 + ((lane>>4)<<3) + e;
    float val = (g<40 && h<80) ? W2[h*40+g] : 0.f;
    fb[15360+i] = (unsigned short)(pk_bf16(val,val) & 0xffffu);
  }
}

__global__ __launch_bounds__(64) void din_kernel(
    const float* __restrict__ q, const float* __restrict__ k, const float* __restrict__ v,
    const int* __restrict__ mask, const float* __restrict__ b1, const float* __restrict__ b2,
    const float* __restrict__ Wf, const float* __restrict__ bf,
    const unsigned short* __restrict__ wfr, float* __restrict__ out)
{
  __shared__ float sm_s[256];
  __shared__ unsigned short tl[224];
  __shared__ __align__(16) unsigned int H_s[32*52];   // [item][52 u32 words] (h-pairs), words 40..47 zero

  const int lane = threadIdx.x;
  const int lg = lane>>4, lc = lane&15;
  const long b = blockIdx.x;
  const float* kb = k + b*(T_LEN*64);
  const float* vb = v + b*(T_LEN*64);
  const int*   mb = mask + b*T_LEN;
  const float* qb = q + b*64;
  const bf8* A1f = (const bf8*)wfr;
  const bf8* A2f = (const bf8*)(wfr + 15360);

  // per-lane q fragments (k-dims lg*8..+8 and 32+lg*8..+8)
  float4 qA0 = *(const float4*)(qb + lg*8);
  float4 qA1 = *(const float4*)(qb + lg*8 + 4);
  float4 qB0 = *(const float4*)(qb + 32 + lg*8);
  float4 qB1 = *(const float4*)(qb + 32 + lg*8 + 4);
  bf8 fq0 = pack8(qA0,qA1);
  bf8 fq1 = pack8(qB0,qB1);

  // per-lane bias / Wf for C/D rows this lane owns (row = *t*16 + lg*4 + r)
  float biasv[20], b2v[12], wfv[12];
  #pragma unroll
  for (int ht=0; ht<5; ++ht)
    #pragma unroll
    for (int r=0;r<4;++r) biasv[ht*4+r] = b1[ht*16 + lg*4 + r];
  #pragma unroll
  for (int gt=0; gt<3; ++gt)
    #pragma unroll
    for (int r=0;r<4;++r){
      int g = gt*16 + lg*4 + r;
      b2v[gt*4+r] = (g<40)? b2[g] : 0.f;
      wfv[gt*4+r] = (g<40)? Wf[g] : 0.f;
    }
  const float bf0 = bf[0];

  // zero H pad words (h 80..95) once
  { uint4 z = {0,0,0,0}; *(uint4*)(H_s + (lane>>1)*52 + 40 + (lane&1)*4) = z; }

  // ---- compaction + logit slot init (wave-local, deterministic) ----
  int tot = 0;
  unsigned long long ltm = (1ull<<lane) - 1ull;
  #pragma unroll
  for (int c=0;c<4;++c){
    int t = c*64 + lane;
    bool f = (t < T_LEN) && (mb[t] != 0);
    unsigned long long bal = __ballot(f);
    sm_s[t] = (t < T_LEN) ? (f ? 0.f : CONST_MIN_F) : -__builtin_inff();
    if (f) tl[tot + (int)__popcll(bal & ltm)] = (unsigned short)t;
    tot += (int)__popcll(bal);
  }
  __syncthreads();

  // ---- passes of 32 items (2 MFMA tiles) ----
  for (int base=0; base<tot; base+=32){
    int t0 = tl[min(base+lc, tot-1)];
    int t1 = tl[min(base+16+lc, tot-1)];
    const float* kr0 = kb + t0*64 + lg*8;
    const float* kr1 = kb + t1*64 + lg*8;
    float4 a00 = *(const float4*)(kr0);
    float4 a01 = *(const float4*)(kr0+4);
    float4 b00 = *(const float4*)(kr0+32);
    float4 b01 = *(const float4*)(kr0+36);
    float4 a10 = *(const float4*)(kr1);
    float4 a11 = *(const float4*)(kr1+4);
    float4 b10 = *(const float4*)(kr1+32);
    float4 b11 = *(const float4*)(kr1+36);
    bf8 f00 = pack8(a00,a01),          f01 = pack8(b00,b01);
    bf8 f02 = pack8m(a00,qA0,a01,qA1), f03 = pack8m(b00,qB0,b01,qB1);
    bf8 f10 = pack8(a10,a11),          f11 = pack8(b10,b11);
    bf8 f12 = pack8m(a10,qA0,a11,qA1), f13 = pack8m(b10,qB0,b11,qB1);

    f32x4 acc0[5], acc1[5];
    #pragma unroll
    for (int ht=0; ht<5; ++ht)
      #pragma unroll
      for (int r=0;r<4;++r){ acc0[ht][r]=biasv[ht*4+r]; acc1[ht][r]=biasv[ht*4+r]; }

    #pragma unroll
    for (int ht=0; ht<5; ++ht){
      bf8 afr;
      afr = A1f[(ht*6+0)*64+lane];
      acc0[ht] = __builtin_amdgcn_mfma_f32_16x16x32_bf16(afr, f00, acc0[ht],0,0,0);
      acc1[ht] = __builtin_amdgcn_mfma_f32_16x16x32_bf16(afr, f10, acc1[ht],0,0,0);
      afr = A1f[(ht*6+1)*64+lane];
      acc0[ht] = __builtin_amdgcn_mfma_f32_16x16x32_bf16(afr, f01, acc0[ht],0,0,0);
      acc1[ht] = __builtin_amdgcn_mfma_f32_16x16x32_bf16(afr, f11, acc1[ht],0,0,0);
      afr = A1f[(ht*6+2)*64+lane];
      acc0[ht] = __builtin_amdgcn_mfma_f32_16x16x32_bf16(afr, f02, acc0[ht],0,0,0);
      acc1[ht] = __builtin_amdgcn_mfma_f32_16x16x32_bf16(afr, f12, acc1[ht],0,0,0);
      afr = A1f[(ht*6+3)*64+lane];
      acc0[ht] = __builtin_amdgcn_mfma_f32_16x16x32_bf16(afr, f03, acc0[ht],0,0,0);
      acc1[ht] = __builtin_amdgcn_mfma_f32_16x16x32_bf16(afr, f13, acc1[ht],0,0,0);
      afr = A1f[(ht*6+4)*64+lane];
      acc0[ht] = __builtin_amdgcn_mfma_f32_16x16x32_bf16(afr, fq0, acc0[ht],0,0,0);
      acc1[ht] = __builtin_amdgcn_mfma_f32_16x16x32_bf16(afr, fq0, acc1[ht],0,0,0);
      afr = A1f[(ht*6+5)*64+lane];
      acc0[ht] = __builtin_amdgcn_mfma_f32_16x16x32_bf16(afr, fq1, acc0[ht],0,0,0);
      acc1[ht] = __builtin_amdgcn_mfma_f32_16x16x32_bf16(afr, fq1, acc1[ht],0,0,0);
    }

    // sigmoid -> H (bf16 pairs), wave-local LDS bounce
    #pragma unroll
    for (int ht=0; ht<5; ++ht){
      #pragma unroll
      for (int rp=0; rp<2; ++rp){
        H_s[lc*52      + ht*8+lg*2+rp] = pk_bf16(sigmoidf_(acc0[ht][2*rp]), sigmoidf_(acc0[ht][2*rp+1]));
        H_s[(16+lc)*52 + ht*8+lg*2+rp] = pk_bf16(sigmoidf_(acc1[ht][2*rp]), sigmoidf_(acc1[ht][2*rp+1]));
      }
    }
    __syncthreads();

    bf8 c0[3], c1[3];
    #pragma unroll
    for (int ks=0; ks<3; ++ks){
      c0[ks] = *(const bf8*)(H_s + lc*52      + 16*ks + 4*lg);
      c1[ks] = *(const bf8*)(H_s + (16+lc)*52 + 16*ks + 4*lg);
    }
    f32x4 g0[3], g1[3];
    #pragma unroll
    for (int gt=0; gt<3; ++gt)
      #pragma unroll
      for (int r=0;r<4;++r){ g0[gt][r]=b2v[gt*4+r]; g1[gt][r]=b2v[gt*4+r]; }
    #pragma unroll
    for (int gt=0; gt<3; ++gt){
      #pragma unroll
      for (int ks=0; ks<3; ++ks){
        bf8 afr = A2f[(gt*3+ks)*64+lane];
        g0[gt] = __builtin_amdgcn_mfma_f32_16x16x32_bf16(afr, c0[ks], g0[gt],0,0,0);
        g1[gt] = __builtin_amdgcn_mfma_f32_16x16x32_bf16(afr, c1[ks], g1[gt],0,0,0);
      }
    }
    float p0=0.f, p1=0.f;
    #pragma unroll
    for (int gt=0; gt<3; ++gt)
      #pragma unroll
      for (int r=0;r<4;++r){
        p0 = fmaf(wfv[gt*4+r], sigmoidf_(g0[gt][r]), p0);
        p1 = fmaf(wfv[gt*4+r], sigmoidf_(g1[gt][r]), p1);
      }
    p0 += __shfl_xor(p0,16); p0 += __shfl_xor(p0,32);
    p1 += __shfl_xor(p1,16); p1 += __shfl_xor(p1,32);
    if (lg==0){
      if (base+lc    < tot) sm_s[tl[base+lc]]    = p0 + bf0;
      if (base+16+lc < tot) sm_s[tl[base+16+lc]] = p1 + bf0;
    }
    __syncthreads();
  }

  // ---- wave-local softmax over 256 slots ----
  float l0=sm_s[lane], l1=sm_s[64+lane], l2=sm_s[128+lane], l3=sm_s[192+lane];
  float m = fmaxf(fmaxf(l0,l1), fmaxf(l2,l3));
  #pragma unroll
  for (int off=1; off<64; off<<=1) m = fmaxf(m, __shfl_xor(m,off));
  float e0=__expf(l0-m), e1=__expf(l1-m), e2=__expf(l2-m), e3=__expf(l3-m);
  float s = e0+e1+e2+e3;
  #pragma unroll
  for (int off=1; off<64; off<<=1) s += __shfl_xor(s,off);
  float inv = 1.0f/s;
  sm_s[lane]=e0*inv; sm_s[64+lane]=e1*inv; sm_s[128+lane]=e2*inv; sm_s[192+lane]=e3*inv;
  __syncthreads();

  // ---- PV: out[b][lane] = sum_t w[t] * v[b][t][lane] ----
  float acc = 0.f;
  if (tot > 0){
    int i=0;
    for (; i+4<=tot; i+=4){
      int ta=tl[i], tb_=tl[i+1], tc_=tl[i+2], td_=tl[i+3];
      float wa=sm_s[ta], wb=sm_s[tb_], wc=sm_s[tc_], wd=sm_s[td_];
      acc = fmaf(wa, vb[ta*64+lane], acc);
      acc = fmaf(wb, vb[tb_*64+lane], acc);
      acc = fmaf(wc, vb[tc_*64+lane], acc);
      acc = fmaf(wd, vb[td_*64+lane], acc);
    }
    for (; i<tot; ++i){ int t=tl[i]; acc = fmaf(sm_s[t], vb[t*64+lane], acc); }
  } else {
    for (int t=0;t<T_LEN;++t) acc = fmaf(sm_s[t], vb[t*64+lane], acc);
  }
  out[b*64+lane] = acc;
}

extern "C" void kernel_launch(void* const* d_in, const int* in_sizes, int n_in,
                              void* d_out, int out_size, void* d_ws, size_t ws_size,
                              hipStream_t stream) {
  const float* q    = (const float*)d_in[0];
  const float* k    = (const float*)d_in[1];
  const float* v    = (const float*)d_in[2];
  const int*   mask = (const int*)d_in[3];
  const float* W1   = (const float*)d_in[4];
  const float* b1   = (const float*)d_in[5];
  const float* W2   = (const float*)d_in[6];
  const float* b2   = (const float*)d_in[7];
  const float* Wf   = (const float*)d_in[8];
  const float* bf   = (const float*)d_in[9];
  float* out = (float*)d_out;
  unsigned short* fb = (unsigned short*)d_ws;   // 19968 ushorts = 39936 B

  hipLaunchKernelGGL(prep_kernel, dim3(60), dim3(256), 0, stream, W1, W2, fb);
  hipLaunchKernelGGL(din_kernel, dim3(2048), dim3(64), 0, stream,
                     q, k, v, mask, b1, b2, Wf, bf, fb, out);
}